// Round 3
// baseline (839.849 us; speedup 1.0000x reference)
//
#include <hip/hip_runtime.h>
#include <stdint.h>

typedef __bf16 bf16_t;
typedef __bf16 bf16x8 __attribute__((ext_vector_type(8)));
typedef __bf16 bf16x4 __attribute__((ext_vector_type(4)));
typedef float f32x4 __attribute__((ext_vector_type(4)));

// Async global->LDS, 16B per lane (wave-uniform base + lane*16).
#define GLOAD16(gp, lp)                                                        \
    __builtin_amdgcn_global_load_lds(                                          \
        (const __attribute__((address_space(1))) void*)(gp),                   \
        (__attribute__((address_space(3))) void*)(lp), 16, 0, 0)

// LDS XOR swizzle (kept from R2: conflicts 3.5e7 -> 0, free):
// data for (row, chunk q) lives at slot q ^ ((row>>1)&3); loader thread t
// fetches global chunk (t&3) ^ ((t>>3)&3).

// ---------------------------------------------------------------------------
// fp32 -> bf16 convert with column-concat placement
// ---------------------------------------------------------------------------
__global__ __launch_bounds__(256) void cvt_kernel(const float* __restrict__ src,
                                                  bf16_t* __restrict__ dst,
                                                  int total4, int cshift,
                                                  int cmask, int ldd, int coff) {
    int i = blockIdx.x * 256 + threadIdx.x;
    if (i >= total4) return;
    int idx = i << 2;
    int r = idx >> cshift;
    int c = idx & cmask;
    float4 v = *(const float4*)(src + idx);
    bf16x4 o = {(bf16_t)v.x, (bf16_t)v.y, (bf16_t)v.z, (bf16_t)v.w};
    *(bf16x4*)(dst + (size_t)r * ldd + coff + c) = o;
}

// ---------------------------------------------------------------------------
// LoRA GEMM, split-K, no LDS staging: t = 0.25 * (A[M x K](bf16) @ Bf[64 x K](fp32)^T)
// -> bf16 into dst columns [coff, coff+64). BM=16/block, wave w owns K/4.
// ---------------------------------------------------------------------------
__global__ __launch_bounds__(256) void lora_kernel(const bf16_t* __restrict__ A,
                                                   int lda,
                                                   const float* __restrict__ Bf,
                                                   int K, bf16_t* __restrict__ dst,
                                                   int ldd, int coff) {
    __shared__ __align__(16) float red[4][4][64][4];  // [wave][jtile][lane][reg] = 16 KB
    const int t = threadIdx.x;
    const int m0 = blockIdx.x * 16;
    const int lane = t & 63, w = t >> 6;
    const int ln15 = lane & 15, q = lane >> 4;
    const int KW = K >> 2;  // per-wave K span

    const bf16_t* pa = A + (size_t)(m0 + ln15) * lda + w * KW + q * 8;
    const float* pb = Bf + (size_t)ln15 * K + w * KW + q * 8;

    const f32x4 z = {0.f, 0.f, 0.f, 0.f};
    f32x4 acc[4];
#pragma unroll
    for (int j = 0; j < 4; ++j) acc[j] = z;

#pragma unroll 4
    for (int k = 0; k < KW; k += 32) {
        bf16x8 av = *(const bf16x8*)(pa + k);
#pragma unroll
        for (int j = 0; j < 4; ++j) {
            const float* pbj = pb + (size_t)j * 16 * K + k;
            float4 f0 = *(const float4*)(pbj);
            float4 f1 = *(const float4*)(pbj + 4);
            bf16x8 bv = {(bf16_t)f0.x, (bf16_t)f0.y, (bf16_t)f0.z, (bf16_t)f0.w,
                         (bf16_t)f1.x, (bf16_t)f1.y, (bf16_t)f1.z, (bf16_t)f1.w};
            acc[j] = __builtin_amdgcn_mfma_f32_16x16x32_bf16(av, bv, acc[j], 0, 0, 0);
        }
    }

#pragma unroll
    for (int j = 0; j < 4; ++j) *(f32x4*)&red[w][j][lane][0] = acc[j];
    __syncthreads();

    {
        const int j = t >> 6, lp = t & 63;
        const int l15 = lp & 15, qp = lp >> 4;
        f32x4 s0 = *(const f32x4*)&red[0][j][lp][0];
        f32x4 s1 = *(const f32x4*)&red[1][j][lp][0];
        f32x4 s2 = *(const f32x4*)&red[2][j][lp][0];
        f32x4 s3 = *(const f32x4*)&red[3][j][lp][0];
        f32x4 s = (s0 + s1) + (s2 + s3);
#pragma unroll
        for (int rg = 0; rg < 4; ++rg) {
            int m = m0 + qp * 4 + rg;
            dst[(size_t)m * ldd + coff + j * 16 + l15] = (bf16_t)(s[rg] * 0.25f);
        }
    }
}

// ---------------------------------------------------------------------------
// GEMM1 fused, wave-specialized: gate_up = X1[8192 x 2112] @ Wc^T + SwiGLU.
// Block tile: 128 M-rows x 64 h-cols. Waves 0,1 = gate (full 4x4 outer
// product, rows 0-63 / 64-127); waves 2,3 = up for the same rows.
// 16 MFMA per 8 LDS fragment reads per wave (m97 intensity, 2x the R2 ratio).
// Epilogue: gate accs -> LDS f32 (padded), 1 barrier, up waves do
// h = u * silu(g) -> bf16 X2 cols [0,4096).
// ---------------------------------------------------------------------------
__global__ __launch_bounds__(256) void gemm1_kernel(const bf16_t* __restrict__ X,
                                                    const bf16_t* __restrict__ Wc,
                                                    bf16_t* __restrict__ X2) {
    constexpr int LDA = 2112, LDW = 2112, LDX2 = 4160, K = 2112;
    __shared__ __align__(16) bf16_t As[128 * 32];
    __shared__ __align__(16) bf16_t Bs[128 * 32];
    __shared__ float Hs[128][65];  // gate handoff, pad 65: 2-way conflicts only
    const int t = threadIdx.x;
    const int n0 = blockIdx.x * 64;   // h column block
    const int m0 = blockIdx.y * 128;  // token rows
    const int lane = t & 63, w = t >> 6;
    const int wrow = w & 1;  // which 64-row half of the M-tile
    const int tg = w >> 1;   // 0 = gate, 1 = up
    const int ln15 = lane & 15, q = lane >> 4;

    const int swz = (((t & 3) ^ ((t >> 3) & 3)) << 3);
    const bf16_t* ga0 = X + (size_t)(m0 + (t >> 2)) * LDA + swz;
    const bf16_t* ga1 = ga0 + (size_t)64 * LDA;
    const bf16_t* gb0 = Wc + (size_t)(n0 + (t >> 2)) * LDW + swz;  // gate rows n0..
    const bf16_t* gb1 = gb0 + (size_t)4096 * LDW;                  // up rows 4096+n0..
    bf16_t* lA0 = As + t * 8;
    bf16_t* lA1 = As + 2048 + t * 8;
    bf16_t* lB0 = Bs + t * 8;          // Bs rows 0-63  = gate
    bf16_t* lB1 = Bs + 2048 + t * 8;   // Bs rows 64-127 = up

    const f32x4 z = {0.f, 0.f, 0.f, 0.f};
    f32x4 acc[4][4];
#pragma unroll
    for (int i = 0; i < 4; ++i)
#pragma unroll
        for (int j = 0; j < 4; ++j) acc[i][j] = z;

    int aoff[4], boff[4];
#pragma unroll
    for (int i = 0; i < 4; ++i) {
        int rowa = wrow * 64 + i * 16 + ln15;
        int rowb = tg * 64 + i * 16 + ln15;
        aoff[i] = rowa * 32 + ((q ^ ((rowa >> 1) & 3)) << 3);
        boff[i] = rowb * 32 + ((q ^ ((rowb >> 1) & 3)) << 3);
    }

    for (int kt = 0; kt < K; kt += 32) {
        GLOAD16(ga0, lA0);
        GLOAD16(ga1, lA1);
        GLOAD16(gb0, lB0);
        GLOAD16(gb1, lB1);
        __syncthreads();
        bf16x8 av[4], bv[4];
#pragma unroll
        for (int i = 0; i < 4; ++i) {
            av[i] = *(const bf16x8*)(As + aoff[i]);
            bv[i] = *(const bf16x8*)(Bs + boff[i]);
        }
#pragma unroll
        for (int i = 0; i < 4; ++i)
#pragma unroll
            for (int j = 0; j < 4; ++j)
                acc[i][j] = __builtin_amdgcn_mfma_f32_16x16x32_bf16(av[i], bv[j], acc[i][j], 0, 0, 0);
        __syncthreads();
        ga0 += 32;
        ga1 += 32;
        gb0 += 32;
        gb1 += 32;
    }

    // ---- SwiGLU epilogue: gate -> LDS, barrier, up waves combine ----
    if (tg == 0) {
#pragma unroll
        for (int i = 0; i < 4; ++i)
#pragma unroll
            for (int j = 0; j < 4; ++j)
#pragma unroll
                for (int rg = 0; rg < 4; ++rg)
                    Hs[wrow * 64 + i * 16 + q * 4 + rg][j * 16 + ln15] = acc[i][j][rg];
    }
    __syncthreads();
    if (tg == 1) {
#pragma unroll
        for (int i = 0; i < 4; ++i)
#pragma unroll
            for (int j = 0; j < 4; ++j)
#pragma unroll
                for (int rg = 0; rg < 4; ++rg) {
                    int lr = wrow * 64 + i * 16 + q * 4 + rg;
                    int lc = j * 16 + ln15;
                    float g = Hs[lr][lc];
                    float u = acc[i][j][rg];
                    float h = u * g / (1.f + __expf(-g));  // up * silu(gate)
                    X2[(size_t)(m0 + lr) * LDX2 + (n0 + lc)] = (bf16_t)h;
                }
    }
}

// ---------------------------------------------------------------------------
// GEMM2: out = X2[8192 x 4160] @ Wdc[2048 x 4160]^T, fp32 out (8192 x 2048).
// ---------------------------------------------------------------------------
__global__ __launch_bounds__(256) void gemm2_kernel(const bf16_t* __restrict__ X2,
                                                    const bf16_t* __restrict__ Wdc,
                                                    float* __restrict__ out) {
    constexpr int LDA = 4160, LDB = 4160, K = 4160, LDO = 2048;
    __shared__ __align__(16) bf16_t As[128 * 32];
    __shared__ __align__(16) bf16_t Bs[128 * 32];
    const int t = threadIdx.x;
    const int n0 = blockIdx.x * 128;
    const int m0 = blockIdx.y * 128;
    const int lane = t & 63, w = t >> 6, wr = w >> 1, wc = w & 1;
    const int ln15 = lane & 15, q = lane >> 4;

    const int swz = (((t & 3) ^ ((t >> 3) & 3)) << 3);
    const bf16_t* ga0 = X2 + (size_t)(m0 + (t >> 2)) * LDA + swz;
    const bf16_t* ga1 = ga0 + (size_t)64 * LDA;
    const bf16_t* gb0 = Wdc + (size_t)(n0 + (t >> 2)) * LDB + swz;
    const bf16_t* gb1 = gb0 + (size_t)64 * LDB;
    bf16_t* lA0 = As + t * 8;
    bf16_t* lA1 = As + 2048 + t * 8;
    bf16_t* lB0 = Bs + t * 8;
    bf16_t* lB1 = Bs + 2048 + t * 8;

    const f32x4 z = {0.f, 0.f, 0.f, 0.f};
    f32x4 acc[4][4];
#pragma unroll
    for (int i = 0; i < 4; ++i)
#pragma unroll
        for (int j = 0; j < 4; ++j) acc[i][j] = z;

    int aoff[4], boff[4];
#pragma unroll
    for (int i = 0; i < 4; ++i) {
        int rowa = wr * 64 + i * 16 + ln15;
        int rowb = wc * 64 + i * 16 + ln15;
        aoff[i] = rowa * 32 + ((q ^ ((rowa >> 1) & 3)) << 3);
        boff[i] = rowb * 32 + ((q ^ ((rowb >> 1) & 3)) << 3);
    }

    for (int kt = 0; kt < K; kt += 32) {
        GLOAD16(ga0, lA0);
        GLOAD16(ga1, lA1);
        GLOAD16(gb0, lB0);
        GLOAD16(gb1, lB1);
        __syncthreads();
        bf16x8 av[4], bv[4];
#pragma unroll
        for (int i = 0; i < 4; ++i) {
            av[i] = *(const bf16x8*)(As + aoff[i]);
            bv[i] = *(const bf16x8*)(Bs + boff[i]);
        }
#pragma unroll
        for (int i = 0; i < 4; ++i)
#pragma unroll
            for (int j = 0; j < 4; ++j)
                acc[i][j] = __builtin_amdgcn_mfma_f32_16x16x32_bf16(av[i], bv[j], acc[i][j], 0, 0, 0);
        __syncthreads();
        ga0 += 32;
        ga1 += 32;
        gb0 += 32;
        gb1 += 32;
    }

#pragma unroll
    for (int i = 0; i < 4; ++i)
#pragma unroll
        for (int j = 0; j < 4; ++j)
#pragma unroll
            for (int rg = 0; rg < 4; ++rg) {
                int m = m0 + wr * 64 + i * 16 + q * 4 + rg;
                int n = n0 + wc * 64 + j * 16 + ln15;
                out[(size_t)m * LDO + n] = acc[i][j][rg];
            }
}

// ---------------------------------------------------------------------------
// Workspace layout (bytes):
//   X1  @ 0         : 8192 x 2112 bf16 = 34,603,008   [x | 0.25*x@A_gu^T]
//   W1  @ 34603008  : 8192 x 2112 bf16 = 34,603,008   [W_gu | B_gu]
//   X2  @ 69206016  : 8192 x 4160 bf16 = 68,157,440   [h | 0.25*h@A_d^T]
//   W2  @ 137363456 : 2048 x 4160 bf16 = 17,039,360   [W_d | B_d]
// ---------------------------------------------------------------------------
extern "C" void kernel_launch(void* const* d_in, const int* in_sizes, int n_in,
                              void* d_out, int out_size, void* d_ws, size_t ws_size,
                              hipStream_t stream) {
    const float* x = (const float*)d_in[0];
    const float* Wgu = (const float*)d_in[1];
    const float* Agu = (const float*)d_in[2];
    const float* Bgu = (const float*)d_in[3];
    const float* Wd = (const float*)d_in[4];
    const float* Ad = (const float*)d_in[5];
    const float* Bd = (const float*)d_in[6];
    float* out = (float*)d_out;

    char* ws = (char*)d_ws;
    bf16_t* X1 = (bf16_t*)(ws);
    bf16_t* W1 = (bf16_t*)(ws + 34603008);
    bf16_t* X2 = (bf16_t*)(ws + 69206016);
    bf16_t* W2 = (bf16_t*)(ws + 137363456);

    // fp32 -> bf16 conversions with K-concat placement
    cvt_kernel<<<16384, 256, 0, stream>>>(x, X1, 4194304, 11, 2047, 2112, 0);
    cvt_kernel<<<16384, 256, 0, stream>>>(Wgu, W1, 4194304, 11, 2047, 2112, 0);
    cvt_kernel<<<512, 256, 0, stream>>>(Bgu, W1, 131072, 6, 63, 2112, 2048);
    cvt_kernel<<<8192, 256, 0, stream>>>(Wd, W2, 2097152, 12, 4095, 4160, 0);
    cvt_kernel<<<128, 256, 0, stream>>>(Bd, W2, 32768, 6, 63, 4160, 4096);

    // t1 = 0.25 * x @ A_gu^T  -> X1 cols [2048,2112)
    lora_kernel<<<512, 256, 0, stream>>>(X1, 2112, Agu, 2048, X1, 2112, 2048);
    // fused gate_up GEMM + SwiGLU -> X2 cols [0,4096)
    gemm1_kernel<<<dim3(64, 64), 256, 0, stream>>>(X1, W1, X2);
    // t2 = 0.25 * h @ A_d^T -> X2 cols [4096,4160)
    lora_kernel<<<512, 256, 0, stream>>>(X2, 4160, Ad, 4096, X2, 4160, 4096);
    // out = X2 @ [W_d|B_d]^T
    gemm2_kernel<<<dim3(16, 64), 256, 0, stream>>>(X2, W2, out);
}

// Round 4
// 790.902 us; speedup vs baseline: 1.0619x; 1.0619x over previous
//
#include <hip/hip_runtime.h>
#include <stdint.h>

typedef __bf16 bf16_t;
typedef __bf16 bf16x8 __attribute__((ext_vector_type(8)));
typedef __bf16 bf16x4 __attribute__((ext_vector_type(4)));
typedef float f32x4 __attribute__((ext_vector_type(4)));

// Async global->LDS, 16B per lane (wave-uniform base + lane*16).
#define GLOAD16(gp, lp)                                                        \
    __builtin_amdgcn_global_load_lds(                                          \
        (const __attribute__((address_space(1))) void*)(gp),                   \
        (__attribute__((address_space(3))) void*)(lp), 16, 0, 0)

// LDS XOR swizzle (R2: conflicts 3.5e7 -> 0, free): data for (row, chunk q)
// lives at slot q ^ ((row>>1)&3); loader thread t fetches global chunk
// (t&3) ^ ((t>>3)&3).

// ---------------------------------------------------------------------------
// All fp32 -> bf16 conversions in ONE launch (5 segments, K-concat placement).
// Segment table (blocks of 256 threads, 1024 elems each):
//   [0,16384)      x   -> X1 cols 0-2048
//   [16384,32768)  Wgu -> W1 cols 0-2048
//   [32768,33280)  Bgu -> W1 cols 2048-2112
//   [33280,41472)  Wd  -> W2 cols 0-4096
//   [41472,41600)  Bd  -> W2 cols 4096-4160
// ---------------------------------------------------------------------------
__global__ __launch_bounds__(256) void cvt_all_kernel(
    const float* __restrict__ x, const float* __restrict__ Wgu,
    const float* __restrict__ Bgu, const float* __restrict__ Wd,
    const float* __restrict__ Bd, bf16_t* __restrict__ X1,
    bf16_t* __restrict__ W1, bf16_t* __restrict__ W2) {
    int b = blockIdx.x;
    const float* src;
    bf16_t* dst;
    int cshift, cmask, ldd, coff, lb;
    if (b < 16384) {
        src = x; dst = X1; cshift = 11; cmask = 2047; ldd = 2112; coff = 0; lb = b;
    } else if (b < 32768) {
        src = Wgu; dst = W1; cshift = 11; cmask = 2047; ldd = 2112; coff = 0; lb = b - 16384;
    } else if (b < 33280) {
        src = Bgu; dst = W1; cshift = 6; cmask = 63; ldd = 2112; coff = 2048; lb = b - 32768;
    } else if (b < 41472) {
        src = Wd; dst = W2; cshift = 12; cmask = 4095; ldd = 4160; coff = 0; lb = b - 33280;
    } else {
        src = Bd; dst = W2; cshift = 6; cmask = 63; ldd = 4160; coff = 4096; lb = b - 41472;
    }
    int idx = (lb * 256 + threadIdx.x) << 2;
    int r = idx >> cshift;
    int c = idx & cmask;
    float4 v = *(const float4*)(src + idx);
    bf16x4 o = {(bf16_t)v.x, (bf16_t)v.y, (bf16_t)v.z, (bf16_t)v.w};
    *(bf16x4*)(dst + (size_t)r * ldd + coff + c) = o;
}

// ---------------------------------------------------------------------------
// LoRA GEMM, split-K, no LDS staging: t = 0.25 * (A[M x K](bf16) @ Bf[64 x K](fp32)^T)
// -> bf16 into dst columns [coff, coff+64). BM=16/block, wave w owns K/4.
// ---------------------------------------------------------------------------
__global__ __launch_bounds__(256) void lora_kernel(const bf16_t* __restrict__ A,
                                                   int lda,
                                                   const float* __restrict__ Bf,
                                                   int K, bf16_t* __restrict__ dst,
                                                   int ldd, int coff) {
    __shared__ __align__(16) float red[4][4][64][4];  // 16 KB
    const int t = threadIdx.x;
    const int m0 = blockIdx.x * 16;
    const int lane = t & 63, w = t >> 6;
    const int ln15 = lane & 15, q = lane >> 4;
    const int KW = K >> 2;

    const bf16_t* pa = A + (size_t)(m0 + ln15) * lda + w * KW + q * 8;
    const float* pb = Bf + (size_t)ln15 * K + w * KW + q * 8;

    const f32x4 z = {0.f, 0.f, 0.f, 0.f};
    f32x4 acc[4];
#pragma unroll
    for (int j = 0; j < 4; ++j) acc[j] = z;

#pragma unroll 4
    for (int k = 0; k < KW; k += 32) {
        bf16x8 av = *(const bf16x8*)(pa + k);
#pragma unroll
        for (int j = 0; j < 4; ++j) {
            const float* pbj = pb + (size_t)j * 16 * K + k;
            float4 f0 = *(const float4*)(pbj);
            float4 f1 = *(const float4*)(pbj + 4);
            bf16x8 bv = {(bf16_t)f0.x, (bf16_t)f0.y, (bf16_t)f0.z, (bf16_t)f0.w,
                         (bf16_t)f1.x, (bf16_t)f1.y, (bf16_t)f1.z, (bf16_t)f1.w};
            acc[j] = __builtin_amdgcn_mfma_f32_16x16x32_bf16(av, bv, acc[j], 0, 0, 0);
        }
    }

#pragma unroll
    for (int j = 0; j < 4; ++j) *(f32x4*)&red[w][j][lane][0] = acc[j];
    __syncthreads();

    {
        const int j = t >> 6, lp = t & 63;
        const int l15 = lp & 15, qp = lp >> 4;
        f32x4 s0 = *(const f32x4*)&red[0][j][lp][0];
        f32x4 s1 = *(const f32x4*)&red[1][j][lp][0];
        f32x4 s2 = *(const f32x4*)&red[2][j][lp][0];
        f32x4 s3 = *(const f32x4*)&red[3][j][lp][0];
        f32x4 s = (s0 + s1) + (s2 + s3);
#pragma unroll
        for (int rg = 0; rg < 4; ++rg) {
            int m = m0 + qp * 4 + rg;
            dst[(size_t)m * ldd + coff + j * 16 + l15] = (bf16_t)(s[rg] * 0.25f);
        }
    }
}

// ---------------------------------------------------------------------------
// GEMM1 fused (R2 form + occupancy bound): gate_up = X1 @ Wc^T + SwiGLU.
// Block: 128 rows x (64 gate + 64 up cols). Wave (wr,wc): 4 av reads,
// 2 gate + 2 up bv reads, 16 MFMA. __launch_bounds__(256,4): cap 128 regs
// -> 4 blocks/CU -> grid 4096 = exactly 4 rounds, +1 wave/SIMD hiding.
// ---------------------------------------------------------------------------
__global__ __launch_bounds__(256, 4) void gemm1_kernel(const bf16_t* __restrict__ X,
                                                       const bf16_t* __restrict__ Wc,
                                                       bf16_t* __restrict__ X2) {
    constexpr int LDA = 2112, LDW = 2112, LDX2 = 4160, K = 2112;
    __shared__ __align__(16) bf16_t As[128 * 32];
    __shared__ __align__(16) bf16_t Bs[128 * 32];
    const int t = threadIdx.x;
    const int n0 = blockIdx.x * 64;
    const int m0 = blockIdx.y * 128;
    const int lane = t & 63, w = t >> 6, wr = w >> 1, wc = w & 1;
    const int ln15 = lane & 15, q = lane >> 4;

    const int swz = (((t & 3) ^ ((t >> 3) & 3)) << 3);
    const bf16_t* ga0 = X + (size_t)(m0 + (t >> 2)) * LDA + swz;
    const bf16_t* ga1 = ga0 + (size_t)64 * LDA;
    const bf16_t* gb0 = Wc + (size_t)(n0 + (t >> 2)) * LDW + swz;  // gate rows
    const bf16_t* gb1 = gb0 + (size_t)4096 * LDW;                  // up rows
    bf16_t* lA0 = As + t * 8;
    bf16_t* lA1 = As + 2048 + t * 8;
    bf16_t* lB0 = Bs + t * 8;
    bf16_t* lB1 = Bs + 2048 + t * 8;

    const f32x4 z = {0.f, 0.f, 0.f, 0.f};
    f32x4 accg[4][2], accu[4][2];
#pragma unroll
    for (int i = 0; i < 4; ++i)
#pragma unroll
        for (int j = 0; j < 2; ++j) {
            accg[i][j] = z;
            accu[i][j] = z;
        }

    int aoff[4], bgoff[2], buoff[2];
#pragma unroll
    for (int i = 0; i < 4; ++i) {
        int row = wr * 64 + i * 16 + ln15;
        aoff[i] = row * 32 + ((q ^ ((row >> 1) & 3)) << 3);
    }
#pragma unroll
    for (int j = 0; j < 2; ++j) {
        int row = wc * 32 + j * 16 + ln15;
        bgoff[j] = row * 32 + ((q ^ ((row >> 1) & 3)) << 3);
        buoff[j] = bgoff[j] + 64 * 32;
    }

    for (int kt = 0; kt < K; kt += 32) {
        GLOAD16(ga0, lA0);
        GLOAD16(ga1, lA1);
        GLOAD16(gb0, lB0);
        GLOAD16(gb1, lB1);
        __syncthreads();
        bf16x8 av[4], bg[2], bu[2];
#pragma unroll
        for (int i = 0; i < 4; ++i) av[i] = *(const bf16x8*)(As + aoff[i]);
#pragma unroll
        for (int j = 0; j < 2; ++j) {
            bg[j] = *(const bf16x8*)(Bs + bgoff[j]);
            bu[j] = *(const bf16x8*)(Bs + buoff[j]);
        }
#pragma unroll
        for (int i = 0; i < 4; ++i)
#pragma unroll
            for (int j = 0; j < 2; ++j) {
                accg[i][j] = __builtin_amdgcn_mfma_f32_16x16x32_bf16(av[i], bg[j], accg[i][j], 0, 0, 0);
                accu[i][j] = __builtin_amdgcn_mfma_f32_16x16x32_bf16(av[i], bu[j], accu[i][j], 0, 0, 0);
            }
        __syncthreads();
        ga0 += 32;
        ga1 += 32;
        gb0 += 32;
        gb1 += 32;
    }

#pragma unroll
    for (int i = 0; i < 4; ++i)
#pragma unroll
        for (int j = 0; j < 2; ++j)
#pragma unroll
            for (int rg = 0; rg < 4; ++rg) {
                int m = m0 + wr * 64 + i * 16 + q * 4 + rg;
                int d = n0 + wc * 32 + j * 16 + ln15;
                float g = accg[i][j][rg];
                float u = accu[i][j][rg];
                float h = u * g / (1.f + __expf(-g));  // up * silu(gate)
                X2[(size_t)m * LDX2 + d] = (bf16_t)h;
            }
}

// ---------------------------------------------------------------------------
// GEMM2: out = X2[8192 x 4160] @ Wdc[2048 x 4160]^T, fp32 out.
// __launch_bounds__(256,4): 4 blocks/CU -> grid 1024 = exactly 1 round.
// ---------------------------------------------------------------------------
__global__ __launch_bounds__(256, 4) void gemm2_kernel(const bf16_t* __restrict__ X2,
                                                       const bf16_t* __restrict__ Wdc,
                                                       float* __restrict__ out) {
    constexpr int LDA = 4160, LDB = 4160, K = 4160, LDO = 2048;
    __shared__ __align__(16) bf16_t As[128 * 32];
    __shared__ __align__(16) bf16_t Bs[128 * 32];
    const int t = threadIdx.x;
    const int n0 = blockIdx.x * 128;
    const int m0 = blockIdx.y * 128;
    const int lane = t & 63, w = t >> 6, wr = w >> 1, wc = w & 1;
    const int ln15 = lane & 15, q = lane >> 4;

    const int swz = (((t & 3) ^ ((t >> 3) & 3)) << 3);
    const bf16_t* ga0 = X2 + (size_t)(m0 + (t >> 2)) * LDA + swz;
    const bf16_t* ga1 = ga0 + (size_t)64 * LDA;
    const bf16_t* gb0 = Wdc + (size_t)(n0 + (t >> 2)) * LDB + swz;
    const bf16_t* gb1 = gb0 + (size_t)64 * LDB;
    bf16_t* lA0 = As + t * 8;
    bf16_t* lA1 = As + 2048 + t * 8;
    bf16_t* lB0 = Bs + t * 8;
    bf16_t* lB1 = Bs + 2048 + t * 8;

    const f32x4 z = {0.f, 0.f, 0.f, 0.f};
    f32x4 acc[4][4];
#pragma unroll
    for (int i = 0; i < 4; ++i)
#pragma unroll
        for (int j = 0; j < 4; ++j) acc[i][j] = z;

    int aoff[4], boff[4];
#pragma unroll
    for (int i = 0; i < 4; ++i) {
        int rowa = wr * 64 + i * 16 + ln15;
        int rowb = wc * 64 + i * 16 + ln15;
        aoff[i] = rowa * 32 + ((q ^ ((rowa >> 1) & 3)) << 3);
        boff[i] = rowb * 32 + ((q ^ ((rowb >> 1) & 3)) << 3);
    }

    for (int kt = 0; kt < K; kt += 32) {
        GLOAD16(ga0, lA0);
        GLOAD16(ga1, lA1);
        GLOAD16(gb0, lB0);
        GLOAD16(gb1, lB1);
        __syncthreads();
        bf16x8 av[4], bv[4];
#pragma unroll
        for (int i = 0; i < 4; ++i) {
            av[i] = *(const bf16x8*)(As + aoff[i]);
            bv[i] = *(const bf16x8*)(Bs + boff[i]);
        }
#pragma unroll
        for (int i = 0; i < 4; ++i)
#pragma unroll
            for (int j = 0; j < 4; ++j)
                acc[i][j] = __builtin_amdgcn_mfma_f32_16x16x32_bf16(av[i], bv[j], acc[i][j], 0, 0, 0);
        __syncthreads();
        ga0 += 32;
        ga1 += 32;
        gb0 += 32;
        gb1 += 32;
    }

#pragma unroll
    for (int i = 0; i < 4; ++i)
#pragma unroll
        for (int j = 0; j < 4; ++j)
#pragma unroll
            for (int rg = 0; rg < 4; ++rg) {
                int m = m0 + wr * 64 + i * 16 + q * 4 + rg;
                int n = n0 + wc * 64 + j * 16 + ln15;
                out[(size_t)m * LDO + n] = acc[i][j][rg];
            }
}

// ---------------------------------------------------------------------------
// Workspace layout (bytes):
//   X1  @ 0         : 8192 x 2112 bf16   [x | 0.25*x@A_gu^T]
//   W1  @ 34603008  : 8192 x 2112 bf16   [W_gu | B_gu]
//   X2  @ 69206016  : 8192 x 4160 bf16   [h | 0.25*h@A_d^T]
//   W2  @ 137363456 : 2048 x 4160 bf16   [W_d | B_d]
// ---------------------------------------------------------------------------
extern "C" void kernel_launch(void* const* d_in, const int* in_sizes, int n_in,
                              void* d_out, int out_size, void* d_ws, size_t ws_size,
                              hipStream_t stream) {
    const float* x = (const float*)d_in[0];
    const float* Wgu = (const float*)d_in[1];
    const float* Agu = (const float*)d_in[2];
    const float* Bgu = (const float*)d_in[3];
    const float* Wd = (const float*)d_in[4];
    const float* Ad = (const float*)d_in[5];
    const float* Bd = (const float*)d_in[6];
    float* out = (float*)d_out;

    char* ws = (char*)d_ws;
    bf16_t* X1 = (bf16_t*)(ws);
    bf16_t* W1 = (bf16_t*)(ws + 34603008);
    bf16_t* X2 = (bf16_t*)(ws + 69206016);
    bf16_t* W2 = (bf16_t*)(ws + 137363456);

    // all fp32 -> bf16 conversions, single launch
    cvt_all_kernel<<<41600, 256, 0, stream>>>(x, Wgu, Bgu, Wd, Bd, X1, W1, W2);

    // t1 = 0.25 * x @ A_gu^T  -> X1 cols [2048,2112)
    lora_kernel<<<512, 256, 0, stream>>>(X1, 2112, Agu, 2048, X1, 2112, 2048);
    // fused gate_up GEMM + SwiGLU -> X2 cols [0,4096)
    gemm1_kernel<<<dim3(64, 64), 256, 0, stream>>>(X1, W1, X2);
    // t2 = 0.25 * h @ A_d^T -> X2 cols [4096,4160)
    lora_kernel<<<512, 256, 0, stream>>>(X2, 4160, Ad, 4096, X2, 4160, 4096);
    // out = X2 @ [W_d|B_d]^T
    gemm2_kernel<<<dim3(16, 64), 256, 0, stream>>>(X2, W2, out);
}

// Round 5
// 635.305 us; speedup vs baseline: 1.3220x; 1.2449x over previous
//
#include <hip/hip_runtime.h>
#include <stdint.h>

typedef __bf16 bf16_t;
typedef __bf16 bf16x8 __attribute__((ext_vector_type(8)));
typedef __bf16 bf16x4 __attribute__((ext_vector_type(4)));
typedef float f32x4 __attribute__((ext_vector_type(4)));

// Async global->LDS, 16B per lane (wave-uniform base + lane*16).
#define GLOAD16(gp, lp)                                                        \
    __builtin_amdgcn_global_load_lds(                                          \
        (const __attribute__((address_space(1))) void*)(gp),                   \
        (__attribute__((address_space(3))) void*)(lp), 16, 0, 0)

// BK=64 LDS tiles: row = 64 bf16 = 128 B = exactly 32 banks, so unswizzled
// rows would all start at bank 0 (16-way conflicts). Swizzle: the 16B chunk
// c of row r lives in slot c ^ (r & 7). Loader thread t (row = t>>3,
// slot = t&7) fetches global chunk (t&7) ^ ((t>>3)&7); LDS dest stays
// linear t*16B (wave-uniform + lane*16 as global_load_lds requires).
// Readers: 16 rows x fixed chunk -> slots spread over all 8 -> 2-way = free.

// ---------------------------------------------------------------------------
// All fp32 -> bf16 conversions in ONE launch (7 segments).
//   [0,16384)       x   -> X1 cols 0-2048     (ld 2112)
//   [16384,32768)   Wgu -> W1 cols 0-2048     (ld 2112)
//   [32768,33280)   Bgu -> W1 cols 2048-2112  (ld 2112)
//   [33280,41472)   Wd  -> W2 cols 0-4096     (ld 4160)
//   [41472,41600)   Bd  -> W2 cols 4096-4160  (ld 4160)
//   [41600,41728)   Agu -> Abf  (identity, ld 2048)
//   [41728,41984)   Ad  -> Adbf (identity, ld 4096)
// ---------------------------------------------------------------------------
__global__ __launch_bounds__(256) void cvt_all_kernel(
    const float* __restrict__ x, const float* __restrict__ Wgu,
    const float* __restrict__ Bgu, const float* __restrict__ Wd,
    const float* __restrict__ Bd, const float* __restrict__ Agu,
    const float* __restrict__ Ad, bf16_t* __restrict__ X1,
    bf16_t* __restrict__ W1, bf16_t* __restrict__ W2,
    bf16_t* __restrict__ Abf, bf16_t* __restrict__ Adbf) {
    int b = blockIdx.x;
    const float* src;
    bf16_t* dst;
    int cshift, cmask, ldd, coff, lb;
    if (b < 16384) {
        src = x; dst = X1; cshift = 11; cmask = 2047; ldd = 2112; coff = 0; lb = b;
    } else if (b < 32768) {
        src = Wgu; dst = W1; cshift = 11; cmask = 2047; ldd = 2112; coff = 0; lb = b - 16384;
    } else if (b < 33280) {
        src = Bgu; dst = W1; cshift = 6; cmask = 63; ldd = 2112; coff = 2048; lb = b - 32768;
    } else if (b < 41472) {
        src = Wd; dst = W2; cshift = 12; cmask = 4095; ldd = 4160; coff = 0; lb = b - 33280;
    } else if (b < 41600) {
        src = Bd; dst = W2; cshift = 6; cmask = 63; ldd = 4160; coff = 4096; lb = b - 41472;
    } else if (b < 41728) {
        src = Agu; dst = Abf; cshift = 11; cmask = 2047; ldd = 2048; coff = 0; lb = b - 41600;
    } else {
        src = Ad; dst = Adbf; cshift = 12; cmask = 4095; ldd = 4096; coff = 0; lb = b - 41728;
    }
    int idx = (lb * 256 + threadIdx.x) << 2;
    int r = idx >> cshift;
    int c = idx & cmask;
    float4 v = *(const float4*)(src + idx);
    bf16x4 o = {(bf16_t)v.x, (bf16_t)v.y, (bf16_t)v.z, (bf16_t)v.w};
    *(bf16x4*)(dst + (size_t)r * ldd + coff + c) = o;
}

// ---------------------------------------------------------------------------
// LoRA GEMM, LDS-staged (coalesced): t = 0.25 * (A[M x K] @ Bw[64 x K]^T),
// bf16 out into dst cols [coff,coff+64). BM=64/block, BK=64, 4 waves each
// own 16 rows x 64 cols. grid = M/64.
// ---------------------------------------------------------------------------
__global__ __launch_bounds__(256) void lora_kernel(const bf16_t* __restrict__ A,
                                                   int lda,
                                                   const bf16_t* __restrict__ Bw,
                                                   int K, bf16_t* __restrict__ dst,
                                                   int ldd, int coff) {
    __shared__ __align__(16) bf16_t As[64 * 64];
    __shared__ __align__(16) bf16_t Bs[64 * 64];
    const int t = threadIdx.x;
    const int m0 = blockIdx.x * 64;
    const int lane = t & 63, w = t >> 6;
    const int ln15 = lane & 15, q = lane >> 4;

    const int lrow = t >> 3;
    const int lchunk = (t & 7) ^ (lrow & 7);
    const bf16_t* gaL = A + (size_t)(m0 + lrow) * lda + lchunk * 8;
    const bf16_t* gbL = Bw + (size_t)lrow * K + lchunk * 8;
    bf16_t* lA = As + t * 8;
    bf16_t* lB = Bs + t * 8;

    const f32x4 z = {0.f, 0.f, 0.f, 0.f};
    f32x4 acc[4];
#pragma unroll
    for (int j = 0; j < 4; ++j) acc[j] = z;

    int aoffs[2], boffs[2][4];
#pragma unroll
    for (int s = 0; s < 2; ++s) {
        int rowa = w * 16 + ln15;
        aoffs[s] = rowa * 64 + (((q + 4 * s) ^ (rowa & 7)) << 3);
#pragma unroll
        for (int j = 0; j < 4; ++j) {
            int rowb = j * 16 + ln15;
            boffs[s][j] = rowb * 64 + (((q + 4 * s) ^ (rowb & 7)) << 3);
        }
    }

    for (int kt = 0; kt < K; kt += 64) {
        GLOAD16(gaL, lA);
        GLOAD16(gaL + (size_t)32 * lda, lA + 32 * 64);
        GLOAD16(gbL, lB);
        GLOAD16(gbL + (size_t)32 * K, lB + 32 * 64);
        __syncthreads();
#pragma unroll
        for (int s = 0; s < 2; ++s) {
            bf16x8 av = *(const bf16x8*)(As + aoffs[s]);
#pragma unroll
            for (int j = 0; j < 4; ++j) {
                bf16x8 bv = *(const bf16x8*)(Bs + boffs[s][j]);
                acc[j] = __builtin_amdgcn_mfma_f32_16x16x32_bf16(av, bv, acc[j], 0, 0, 0);
            }
        }
        __syncthreads();
        gaL += 64;
        gbL += 64;
    }

#pragma unroll
    for (int j = 0; j < 4; ++j)
#pragma unroll
        for (int rg = 0; rg < 4; ++rg) {
            int m = m0 + w * 16 + q * 4 + rg;
            dst[(size_t)m * ldd + coff + j * 16 + ln15] = (bf16_t)(acc[j][rg] * 0.25f);
        }
}

// ---------------------------------------------------------------------------
// GEMM1 fused, BK=64: gate_up = X1[8192 x 2112] @ Wc^T + SwiGLU.
// Block: 128 rows x (64 gate + 64 up cols); 33 K-iters, 32 MFMA/wave/iter.
// LDS 32 KB -> 4 blocks/CU with __launch_bounds__(256,4).
// ---------------------------------------------------------------------------
__global__ __launch_bounds__(256, 4) void gemm1_kernel(const bf16_t* __restrict__ X,
                                                       const bf16_t* __restrict__ Wc,
                                                       bf16_t* __restrict__ X2) {
    constexpr int LDA = 2112, LDW = 2112, LDX2 = 4160, K = 2112;
    __shared__ __align__(16) bf16_t As[128 * 64];
    __shared__ __align__(16) bf16_t Bs[128 * 64];
    const int t = threadIdx.x;
    const int n0 = blockIdx.x * 64;
    const int m0 = blockIdx.y * 128;
    const int lane = t & 63, w = t >> 6, wr = w >> 1, wc = w & 1;
    const int ln15 = lane & 15, q = lane >> 4;

    const int lrow = t >> 3;
    const int lchunk = (t & 7) ^ (lrow & 7);
    const bf16_t* gaL = X + (size_t)(m0 + lrow) * LDA + lchunk * 8;
    const bf16_t* gbgL = Wc + (size_t)(n0 + lrow) * LDW + lchunk * 8;          // gate
    const bf16_t* gbuL = Wc + (size_t)(4096 + n0 + lrow) * LDW + lchunk * 8;   // up
    bf16_t* lA = As + t * 8;
    bf16_t* lB = Bs + t * 8;

    const f32x4 z = {0.f, 0.f, 0.f, 0.f};
    f32x4 accg[4][2], accu[4][2];
#pragma unroll
    for (int i = 0; i < 4; ++i)
#pragma unroll
        for (int j = 0; j < 2; ++j) {
            accg[i][j] = z;
            accu[i][j] = z;
        }

    int aoffs[2][4], bgoffs[2][2];
#pragma unroll
    for (int s = 0; s < 2; ++s) {
#pragma unroll
        for (int i = 0; i < 4; ++i) {
            int row = wr * 64 + i * 16 + ln15;
            aoffs[s][i] = row * 64 + (((q + 4 * s) ^ (row & 7)) << 3);
        }
#pragma unroll
        for (int j = 0; j < 2; ++j) {
            int row = wc * 32 + j * 16 + ln15;
            bgoffs[s][j] = row * 64 + (((q + 4 * s) ^ (row & 7)) << 3);
        }
    }

    for (int kt = 0; kt < K; kt += 64) {
        GLOAD16(gaL, lA);
        GLOAD16(gaL + (size_t)32 * LDA, lA + 32 * 64);
        GLOAD16(gaL + (size_t)64 * LDA, lA + 64 * 64);
        GLOAD16(gaL + (size_t)96 * LDA, lA + 96 * 64);
        GLOAD16(gbgL, lB);
        GLOAD16(gbgL + (size_t)32 * LDW, lB + 32 * 64);
        GLOAD16(gbuL, lB + 64 * 64);
        GLOAD16(gbuL + (size_t)32 * LDW, lB + 96 * 64);
        __syncthreads();
#pragma unroll
        for (int s = 0; s < 2; ++s) {
            bf16x8 av[4], bg[2], bu[2];
#pragma unroll
            for (int i = 0; i < 4; ++i) av[i] = *(const bf16x8*)(As + aoffs[s][i]);
#pragma unroll
            for (int j = 0; j < 2; ++j) {
                bg[j] = *(const bf16x8*)(Bs + bgoffs[s][j]);
                bu[j] = *(const bf16x8*)(Bs + bgoffs[s][j] + 64 * 64);  // (row+64)&7 == row&7
            }
#pragma unroll
            for (int i = 0; i < 4; ++i)
#pragma unroll
                for (int j = 0; j < 2; ++j) {
                    accg[i][j] = __builtin_amdgcn_mfma_f32_16x16x32_bf16(av[i], bg[j], accg[i][j], 0, 0, 0);
                    accu[i][j] = __builtin_amdgcn_mfma_f32_16x16x32_bf16(av[i], bu[j], accu[i][j], 0, 0, 0);
                }
        }
        __syncthreads();
        gaL += 64;
        gbgL += 64;
        gbuL += 64;
    }

#pragma unroll
    for (int i = 0; i < 4; ++i)
#pragma unroll
        for (int j = 0; j < 2; ++j)
#pragma unroll
            for (int rg = 0; rg < 4; ++rg) {
                int m = m0 + wr * 64 + i * 16 + q * 4 + rg;
                int d = n0 + wc * 32 + j * 16 + ln15;
                float g = accg[i][j][rg];
                float u = accu[i][j][rg];
                float h = u * g / (1.f + __expf(-g));  // up * silu(gate)
                X2[(size_t)m * LDX2 + d] = (bf16_t)h;
            }
}

// ---------------------------------------------------------------------------
// GEMM2, BK=64: out = X2[8192 x 4160] @ Wdc[2048 x 4160]^T, fp32 out.
// 65 K-iters, 32 MFMA/wave/iter. grid 1024 = 1 round at 4 blocks/CU.
// ---------------------------------------------------------------------------
__global__ __launch_bounds__(256, 4) void gemm2_kernel(const bf16_t* __restrict__ X2,
                                                       const bf16_t* __restrict__ Wdc,
                                                       float* __restrict__ out) {
    constexpr int LDA = 4160, LDB = 4160, K = 4160, LDO = 2048;
    __shared__ __align__(16) bf16_t As[128 * 64];
    __shared__ __align__(16) bf16_t Bs[128 * 64];
    const int t = threadIdx.x;
    const int n0 = blockIdx.x * 128;
    const int m0 = blockIdx.y * 128;
    const int lane = t & 63, w = t >> 6, wr = w >> 1, wc = w & 1;
    const int ln15 = lane & 15, q = lane >> 4;

    const int lrow = t >> 3;
    const int lchunk = (t & 7) ^ (lrow & 7);
    const bf16_t* gaL = X2 + (size_t)(m0 + lrow) * LDA + lchunk * 8;
    const bf16_t* gbL = Wdc + (size_t)(n0 + lrow) * LDB + lchunk * 8;
    bf16_t* lA = As + t * 8;
    bf16_t* lB = Bs + t * 8;

    const f32x4 z = {0.f, 0.f, 0.f, 0.f};
    f32x4 acc[4][4];
#pragma unroll
    for (int i = 0; i < 4; ++i)
#pragma unroll
        for (int j = 0; j < 4; ++j) acc[i][j] = z;

    int aoffs[2][4], boffs[2][4];
#pragma unroll
    for (int s = 0; s < 2; ++s)
#pragma unroll
        for (int i = 0; i < 4; ++i) {
            int rowa = wr * 64 + i * 16 + ln15;
            int rowb = wc * 64 + i * 16 + ln15;
            aoffs[s][i] = rowa * 64 + (((q + 4 * s) ^ (rowa & 7)) << 3);
            boffs[s][i] = rowb * 64 + (((q + 4 * s) ^ (rowb & 7)) << 3);
        }

    for (int kt = 0; kt < K; kt += 64) {
        GLOAD16(gaL, lA);
        GLOAD16(gaL + (size_t)32 * LDA, lA + 32 * 64);
        GLOAD16(gaL + (size_t)64 * LDA, lA + 64 * 64);
        GLOAD16(gaL + (size_t)96 * LDA, lA + 96 * 64);
        GLOAD16(gbL, lB);
        GLOAD16(gbL + (size_t)32 * LDB, lB + 32 * 64);
        GLOAD16(gbL + (size_t)64 * LDB, lB + 64 * 64);
        GLOAD16(gbL + (size_t)96 * LDB, lB + 96 * 64);
        __syncthreads();
#pragma unroll
        for (int s = 0; s < 2; ++s) {
            bf16x8 av[4], bv[4];
#pragma unroll
            for (int i = 0; i < 4; ++i) {
                av[i] = *(const bf16x8*)(As + aoffs[s][i]);
                bv[i] = *(const bf16x8*)(Bs + boffs[s][i]);
            }
#pragma unroll
            for (int i = 0; i < 4; ++i)
#pragma unroll
                for (int j = 0; j < 4; ++j)
                    acc[i][j] = __builtin_amdgcn_mfma_f32_16x16x32_bf16(av[i], bv[j], acc[i][j], 0, 0, 0);
        }
        __syncthreads();
        gaL += 64;
        gbL += 64;
    }

#pragma unroll
    for (int i = 0; i < 4; ++i)
#pragma unroll
        for (int j = 0; j < 4; ++j)
#pragma unroll
            for (int rg = 0; rg < 4; ++rg) {
                int m = m0 + wr * 64 + i * 16 + q * 4 + rg;
                int n = n0 + wc * 64 + j * 16 + ln15;
                out[(size_t)m * LDO + n] = acc[i][j][rg];
            }
}

// ---------------------------------------------------------------------------
// Workspace layout (bytes):
//   X1   @ 0         : 8192 x 2112 bf16   [x | 0.25*x@A_gu^T]
//   W1   @ 34603008  : 8192 x 2112 bf16   [W_gu | B_gu]
//   X2   @ 69206016  : 8192 x 4160 bf16   [h | 0.25*h@A_d^T]
//   W2   @ 137363456 : 2048 x 4160 bf16   [W_d | B_d]
//   Abf  @ 154402816 : 64 x 2048 bf16
//   Adbf @ 154664960 : 64 x 4096 bf16
// ---------------------------------------------------------------------------
extern "C" void kernel_launch(void* const* d_in, const int* in_sizes, int n_in,
                              void* d_out, int out_size, void* d_ws, size_t ws_size,
                              hipStream_t stream) {
    const float* x = (const float*)d_in[0];
    const float* Wgu = (const float*)d_in[1];
    const float* Agu = (const float*)d_in[2];
    const float* Bgu = (const float*)d_in[3];
    const float* Wd = (const float*)d_in[4];
    const float* Ad = (const float*)d_in[5];
    const float* Bd = (const float*)d_in[6];
    float* out = (float*)d_out;

    char* ws = (char*)d_ws;
    bf16_t* X1 = (bf16_t*)(ws);
    bf16_t* W1 = (bf16_t*)(ws + 34603008);
    bf16_t* X2 = (bf16_t*)(ws + 69206016);
    bf16_t* W2 = (bf16_t*)(ws + 137363456);
    bf16_t* Abf = (bf16_t*)(ws + 154402816);
    bf16_t* Adbf = (bf16_t*)(ws + 154664960);

    // all fp32 -> bf16 conversions, single launch
    cvt_all_kernel<<<41984, 256, 0, stream>>>(x, Wgu, Bgu, Wd, Bd, Agu, Ad,
                                              X1, W1, W2, Abf, Adbf);

    // t1 = 0.25 * x @ A_gu^T  -> X1 cols [2048,2112)
    lora_kernel<<<128, 256, 0, stream>>>(X1, 2112, Abf, 2048, X1, 2112, 2048);
    // fused gate_up GEMM + SwiGLU -> X2 cols [0,4096)
    gemm1_kernel<<<dim3(64, 64), 256, 0, stream>>>(X1, W1, X2);
    // t2 = 0.25 * h @ A_d^T -> X2 cols [4096,4160)
    lora_kernel<<<128, 256, 0, stream>>>(X2, 4160, Adbf, 4096, X2, 4160, 4096);
    // out = X2 @ [W_d|B_d]^T
    gemm2_kernel<<<dim3(16, 64), 256, 0, stream>>>(X2, W2, out);
}